// Round 5
// baseline (418.871 us; speedup 1.0000x reference)
//
#include <hip/hip_runtime.h>
#include <math.h>

#define NBATCH 8
#define NFRAME 400
#define NHARM  100
#define NBAND  65
#define SRATE  16000
#define BLK    128
#define NSAMP  (NFRAME*BLK)      // 51200 samples per batch
#define IMPN   16384             // impulse padded to 64*256
#define PI_D   3.14159265358979323846

// workspace layout (byte offsets, all 16B aligned)
#define OFF_PREFIX 0             // double[8*400]        = 25600 B
#define OFF_AMPS   25600         // float[8*400*100]     = 1280000 B
#define OFF_NZ     1305600       // float[8*400*128]     = 1638400 B
#define OFF_SIG    2944000       // float[8*51200]       = 1638400 B
#define OFF_IMP    4582400       // float[16384]         = 65536 B
// total ~4.65 MB

__device__ __forceinline__ float scale_fn(float x) {
    float s = 1.0f / (1.0f + expf(-x));
    return 2.0f * powf(s, 2.3025851f) + 1e-7f;   // log(10) = 2.302585093
}

// --- exclusive prefix sum of pitch per batch (fp64), 8 serial chains ---
__global__ void k_prefix(const float* __restrict__ pitch, double* __restrict__ prefix) {
    int b = threadIdx.x;
    if (b < NBATCH) {
        double s = 0.0;
        const float* p = pitch + b * NFRAME;
        double* o = prefix + b * NFRAME;
        for (int f = 0; f < NFRAME; ++f) { o[f] = s; s += (double)p[f]; }
    }
}

// --- reverb impulse: imp[0]=1; imp[t]=rn[t]*exp(-c*t)*sigmoid(wet), zero-pad to 16384 ---
__global__ void k_imp(const float* __restrict__ rn, const float* __restrict__ decay,
                      const float* __restrict__ wet, float* __restrict__ imp) {
    int t = blockIdx.x * blockDim.x + threadIdx.x;
    if (t >= IMPN) return;
    double c  = log1p(exp(-(double)decay[0])) * (500.0 / (double)SRATE); // per-sample rate
    double wg = 1.0 / (1.0 + exp(-(double)wet[0]));
    float v;
    if (t == 0)            v = 1.0f;
    else if (t < SRATE)    v = rn[t] * (float)(exp(-c * (double)t) * wg);
    else                   v = 0.0f;
    imp[t] = v;
}

// --- per (b,f) frame: normalized harmonic amps, filtered-noise ir, nz = conv(noise, ir) ---
__global__ void k_frame(const float* __restrict__ amp_param, const float* __restrict__ noise_param,
                        const float* __restrict__ pitch, const float* __restrict__ noise,
                        float* __restrict__ amps_ws, float* __restrict__ nz_ws) {
    __shared__ float s_amps[NHARM];
    __shared__ float s_np[NBAND];
    __shared__ float s_ct[BLK];
    __shared__ float s_ir[BLK];
    __shared__ float s_noise[BLK];
    __shared__ float s_red[BLK];
    __shared__ float s_total;

    int bf = blockIdx.x;
    int tid = threadIdx.x;
    float pf = pitch[bf];

    if (tid < NHARM + 1) {
        float p = scale_fn(amp_param[bf * (NHARM + 1) + tid]);
        if (tid == 0) s_total = p;
        else {
            // aa = (pitch*k < sr/2) + 1e-4  -> 1.0001 or 0.0001, k = tid
            float aa = (pf * (float)tid < 8000.0f) ? 1.0001f : 0.0001f;
            s_amps[tid - 1] = p * aa;
        }
    }
    if (tid < NBAND) s_np[tid] = scale_fn(noise_param[bf * NBAND + tid] - 5.0f);
    s_ct[tid]    = (float)cos(2.0 * PI_D * (double)tid / 128.0);
    s_noise[tid] = noise[bf * BLK + tid];
    __syncthreads();

    // ir[n] = irfft(np)[n] * (0.5 + 0.5*cos(2*pi*n/128))  (roll/hann/roll collapsed)
    float irv;
    {
        int n = tid;
        float a = s_np[0];
        #pragma unroll
        for (int k = 1; k < NBAND - 1; ++k) a += 2.0f * s_np[k] * s_ct[(k * n) & 127];
        a += s_np[NBAND - 1] * s_ct[(64 * n) & 127];
        a *= (1.0f / 128.0f);
        a *= 0.5f + 0.5f * s_ct[n];
        irv = a;
    }

    // sum of masked amps (tree reduce over 128, entries >=100 are 0)
    s_red[tid] = (tid < NHARM) ? s_amps[tid] : 0.0f;
    __syncthreads();
    for (int s = 64; s > 0; s >>= 1) {
        if (tid < s) s_red[tid] += s_red[tid + s];
        __syncthreads();
    }
    if (tid < NHARM) {
        float v = s_amps[tid] / s_red[0] * s_total;
        amps_ws[bf * NHARM + tid] = v;
    }
    s_ir[tid] = irv;
    __syncthreads();

    // nz[p] = sum_{m<=p} noise[m] * ir[p-m]
    {
        int p = tid;
        float acc = 0.0f;
        for (int m = 0; m <= p; ++m) acc += s_noise[m] * s_ir[p - m];
        nz_ws[bf * BLK + p] = acc;
    }
}

// --- harmonic synth + add nz -> signal ---
__global__ void k_harm(const float* __restrict__ pitch, const double* __restrict__ prefix,
                       const float* __restrict__ amps_ws, const float* __restrict__ nz_ws,
                       float* __restrict__ sig) {
    __shared__ float s_amps[NHARM];
    int bf = blockIdx.x;
    int tid = threadIdx.x;
    if (tid < NHARM) s_amps[tid] = amps_ws[bf * NHARM + tid];
    __syncthreads();

    float pf = pitch[bf];
    // omega[n] (inclusive cumsum) = 2pi/sr * (128*prefix_excl + (r+1)*pitch)
    double om = (2.0 * PI_D / (double)SRATE) *
                (128.0 * prefix[bf] + (double)(tid + 1) * (double)pf);
    float th = (float)fmod(om, 2.0 * PI_D);   // exact for integer-k harmonics
    float h = 0.0f;
    #pragma unroll 4
    for (int k = 1; k <= NHARM; ++k) h += sinf(th * (float)k) * s_amps[k - 1];
    int idx = bf * BLK + tid;
    sig[idx] = h + nz_ws[idx];
}

// --- reverb: out[p] = sum_{t<=p, t<16000} imp[t]*sig[p-t] ---
// Sliding-window version: each thread owns 16 CONSECUTIVE outputs; per 4-tap
// group it reads ONE new float4 from LDS (XOR-swizzled to kill the 64B-stride
// 32-way bank conflict) and performs 64 FMAs. Tap range split across blocks,
// partials accumulated into out via atomicAdd (out pre-zeroed).
#define RTILE 2048     // outputs per tile (128 thr x 16)
#define RCT   256      // taps per chunk
#define RKTH  128      // threads
#define RCH   4        // chunks per block segment
#define RMAXSEG 16     // ceil(63 / RCH)
#define NTILES (NSAMP / RTILE)   // 25 per batch
#define RWIN  (RTILE + RCT)      // 2304 floats
#define RWIN4 (RWIN / 4)         // 576 float4 (multiple of 8 -> swizzle closed)

__device__ __forceinline__ int swz4(int F) { return F ^ ((F >> 3) & 7); }

__global__ __launch_bounds__(RKTH) void k_reverb3(const float* __restrict__ sig,
                                                  const float* __restrict__ imp,
                                                  float* __restrict__ out) {
    __shared__ __align__(16) float s_sig[RWIN];

    int bid  = blockIdx.x;
    int seg  = bid % RMAXSEG;
    int bt   = bid / RMAXSEG;
    int b    = bt / NTILES;
    int tile = bt % NTILES;
    int P0   = tile * RTILE;
    int nch  = (P0 + RTILE) / RCT;             // taps needed: t <= P0+RTILE-1
    if (nch > 63) nch = 63;                    // imp zero beyond 16128
    int c0 = seg * RCH;
    if (c0 >= nch) return;
    int c1 = c0 + RCH; if (c1 > nch) c1 = nch;

    int tid = threadIdx.x;
    const float* sb = sig + b * NSAMP;

    float af[16];
    #pragma unroll
    for (int o = 0; o < 16; ++o) af[o] = 0.f;

    // window float4 base for tap-group g: F_low(g) = Fbase - g, window regs
    // w_[m] <-> logical window float l = 4*(Fbase-g) + m,  l = 16*tid + 256 + o - 4g - j
    int Fbase = 4 * tid + (RCT / 4 - 1);       // 4*tid + 63

    for (int c = c0; c < c1; ++c) {
        int T0 = c * RCT;
        int W0 = P0 - T0 - RCT;                // logical window float l <-> sig[W0 + l]
        if (W0 >= 0) {
            #pragma unroll
            for (int it = 0; it < 5; ++it) {
                int F = tid + RKTH * it;
                if (F < RWIN4)
                    *reinterpret_cast<float4*>(&s_sig[4 * swz4(F)]) =
                        *reinterpret_cast<const float4*>(&sb[W0 + 4 * F]);
            }
        } else {
            for (int l = tid; l < RWIN; l += RKTH) {
                int idx = W0 + l;
                float v = (idx >= 0) ? sb[idx] : 0.0f;
                s_sig[4 * swz4(l >> 2) + (l & 3)] = v;
            }
        }
        __syncthreads();

        const float4* imp4 = reinterpret_cast<const float4*>(imp + T0);  // uniform -> s_load
        float w_[20];
        #pragma unroll
        for (int k = 0; k < 5; ++k) {
            float4 v = *reinterpret_cast<const float4*>(&s_sig[4 * swz4(Fbase + k)]);
            w_[4 * k + 0] = v.x; w_[4 * k + 1] = v.y;
            w_[4 * k + 2] = v.z; w_[4 * k + 3] = v.w;
        }
        #pragma unroll 8
        for (int g = 0; g < RCT / 4; ++g) {
            float4 iq = imp4[g];
            #pragma unroll
            for (int o = 0; o < 16; ++o) {
                af[o] += iq.x * w_[o + 4];
                af[o] += iq.y * w_[o + 3];
                af[o] += iq.z * w_[o + 2];
                af[o] += iq.w * w_[o + 1];
            }
            if (g < RCT / 4 - 1) {
                float4 nv = *reinterpret_cast<const float4*>(&s_sig[4 * swz4(Fbase - 1 - g)]);
                #pragma unroll
                for (int m = 19; m >= 4; --m) w_[m] = w_[m - 4];
                w_[0] = nv.x; w_[1] = nv.y; w_[2] = nv.z; w_[3] = nv.w;
            }
        }
        __syncthreads();
    }

    float* ob = out + b * NSAMP + P0 + 16 * tid;
    #pragma unroll
    for (int o = 0; o < 16; ++o) atomicAdd(&ob[o], af[o]);
}

extern "C" void kernel_launch(void* const* d_in, const int* in_sizes, int n_in,
                              void* d_out, int out_size, void* d_ws, size_t ws_size,
                              hipStream_t stream) {
    const float* amp_param   = (const float*)d_in[0];
    const float* noise_param = (const float*)d_in[1];
    const float* pitch       = (const float*)d_in[2];
    const float* noise       = (const float*)d_in[3];
    const float* rn          = (const float*)d_in[4];
    const float* decay       = (const float*)d_in[5];
    const float* wet         = (const float*)d_in[6];
    float* out = (float*)d_out;

    char* ws = (char*)d_ws;
    double* prefix = (double*)(ws + OFF_PREFIX);
    float*  amps   = (float*)(ws + OFF_AMPS);
    float*  nz     = (float*)(ws + OFF_NZ);
    float*  sig    = (float*)(ws + OFF_SIG);
    float*  imp    = (float*)(ws + OFF_IMP);

    hipMemsetAsync(out, 0, (size_t)out_size * sizeof(float), stream);
    k_prefix<<<dim3(1), dim3(64), 0, stream>>>(pitch, prefix);
    k_imp<<<dim3(IMPN / 256), dim3(256), 0, stream>>>(rn, decay, wet, imp);
    k_frame<<<dim3(NBATCH * NFRAME), dim3(128), 0, stream>>>(amp_param, noise_param, pitch, noise, amps, nz);
    k_harm<<<dim3(NBATCH * NFRAME), dim3(128), 0, stream>>>(pitch, prefix, amps, nz, sig);
    k_reverb3<<<dim3(NBATCH * NTILES * RMAXSEG), dim3(RKTH), 0, stream>>>(sig, imp, out);
}

// Round 6
// 251.560 us; speedup vs baseline: 1.6651x; 1.6651x over previous
//
#include <hip/hip_runtime.h>
#include <math.h>

#define NBATCH 8
#define NFRAME 400
#define NHARM  100
#define NBAND  65
#define SRATE  16000
#define BLK    128
#define NSAMP  (NFRAME*BLK)      // 51200 samples per batch
#define IMPN   16384             // impulse padded to 64*256
#define PI_D   3.14159265358979323846

// workspace layout (byte offsets, all 16B aligned)
#define OFF_PREFIX 0             // double[8*400]        = 25600 B
#define OFF_AMPS   25600         // float[8*400*100]     = 1280000 B
#define OFF_NZ     1305600       // float[8*400*128]     = 1638400 B
#define OFF_SIG    2944000       // float[8*51200]       = 1638400 B
#define OFF_IMP    4582400       // float[16384]         = 65536 B
#define OFF_PART   4647936       // float[8*25*16*2048]  = 26214400 B
#define WS_NEED    (OFF_PART + 26214400)

__device__ __forceinline__ float scale_fn(float x) {
    float s = 1.0f / (1.0f + expf(-x));
    return 2.0f * powf(s, 2.3025851f) + 1e-7f;   // log(10) = 2.302585093
}

// --- exclusive prefix sum of pitch per batch (fp64), 8 serial chains ---
__global__ void k_prefix(const float* __restrict__ pitch, double* __restrict__ prefix) {
    int b = threadIdx.x;
    if (b < NBATCH) {
        double s = 0.0;
        const float* p = pitch + b * NFRAME;
        double* o = prefix + b * NFRAME;
        for (int f = 0; f < NFRAME; ++f) { o[f] = s; s += (double)p[f]; }
    }
}

// --- reverb impulse: imp[0]=1; imp[t]=rn[t]*exp(-c*t)*sigmoid(wet), zero-pad to 16384 ---
__global__ void k_imp(const float* __restrict__ rn, const float* __restrict__ decay,
                      const float* __restrict__ wet, float* __restrict__ imp) {
    int t = blockIdx.x * blockDim.x + threadIdx.x;
    if (t >= IMPN) return;
    double c  = log1p(exp(-(double)decay[0])) * (500.0 / (double)SRATE); // per-sample rate
    double wg = 1.0 / (1.0 + exp(-(double)wet[0]));
    float v;
    if (t == 0)            v = 1.0f;
    else if (t < SRATE)    v = rn[t] * (float)(exp(-c * (double)t) * wg);
    else                   v = 0.0f;
    imp[t] = v;
}

// --- per (b,f) frame: normalized harmonic amps, filtered-noise ir, nz = conv(noise, ir) ---
__global__ void k_frame(const float* __restrict__ amp_param, const float* __restrict__ noise_param,
                        const float* __restrict__ pitch, const float* __restrict__ noise,
                        float* __restrict__ amps_ws, float* __restrict__ nz_ws) {
    __shared__ float s_amps[NHARM];
    __shared__ float s_np[NBAND];
    __shared__ float s_ct[BLK];
    __shared__ float s_ir[BLK];
    __shared__ float s_noise[BLK];
    __shared__ float s_red[BLK];
    __shared__ float s_total;

    int bf = blockIdx.x;
    int tid = threadIdx.x;
    float pf = pitch[bf];

    if (tid < NHARM + 1) {
        float p = scale_fn(amp_param[bf * (NHARM + 1) + tid]);
        if (tid == 0) s_total = p;
        else {
            // aa = (pitch*k < sr/2) + 1e-4  -> 1.0001 or 0.0001, k = tid
            float aa = (pf * (float)tid < 8000.0f) ? 1.0001f : 0.0001f;
            s_amps[tid - 1] = p * aa;
        }
    }
    if (tid < NBAND) s_np[tid] = scale_fn(noise_param[bf * NBAND + tid] - 5.0f);
    s_ct[tid]    = (float)cos(2.0 * PI_D * (double)tid / 128.0);
    s_noise[tid] = noise[bf * BLK + tid];
    __syncthreads();

    // ir[n] = irfft(np)[n] * (0.5 + 0.5*cos(2*pi*n/128))  (roll/hann/roll collapsed)
    float irv;
    {
        int n = tid;
        float a = s_np[0];
        #pragma unroll
        for (int k = 1; k < NBAND - 1; ++k) a += 2.0f * s_np[k] * s_ct[(k * n) & 127];
        a += s_np[NBAND - 1] * s_ct[(64 * n) & 127];
        a *= (1.0f / 128.0f);
        a *= 0.5f + 0.5f * s_ct[n];
        irv = a;
    }

    // sum of masked amps (tree reduce over 128, entries >=100 are 0)
    s_red[tid] = (tid < NHARM) ? s_amps[tid] : 0.0f;
    __syncthreads();
    for (int s = 64; s > 0; s >>= 1) {
        if (tid < s) s_red[tid] += s_red[tid + s];
        __syncthreads();
    }
    if (tid < NHARM) {
        float v = s_amps[tid] / s_red[0] * s_total;
        amps_ws[bf * NHARM + tid] = v;
    }
    s_ir[tid] = irv;
    __syncthreads();

    // nz[p] = sum_{m<=p} noise[m] * ir[p-m]
    {
        int p = tid;
        float acc = 0.0f;
        for (int m = 0; m <= p; ++m) acc += s_noise[m] * s_ir[p - m];
        nz_ws[bf * BLK + p] = acc;
    }
}

// --- harmonic synth + add nz -> signal ---
__global__ void k_harm(const float* __restrict__ pitch, const double* __restrict__ prefix,
                       const float* __restrict__ amps_ws, const float* __restrict__ nz_ws,
                       float* __restrict__ sig) {
    __shared__ float s_amps[NHARM];
    int bf = blockIdx.x;
    int tid = threadIdx.x;
    if (tid < NHARM) s_amps[tid] = amps_ws[bf * NHARM + tid];
    __syncthreads();

    float pf = pitch[bf];
    // omega[n] (inclusive cumsum) = 2pi/sr * (128*prefix_excl + (r+1)*pitch)
    double om = (2.0 * PI_D / (double)SRATE) *
                (128.0 * prefix[bf] + (double)(tid + 1) * (double)pf);
    float th = (float)fmod(om, 2.0 * PI_D);   // exact for integer-k harmonics
    float h = 0.0f;
    #pragma unroll 4
    for (int k = 1; k <= NHARM; ++k) h += sinf(th * (float)k) * s_amps[k - 1];
    int idx = bf * BLK + tid;
    sig[idx] = h + nz_ws[idx];
}

// --- reverb: out[p] = sum_{t<=p, t<16000} imp[t]*sig[p-t] ---
// Sliding-window + tap-split. Each thread owns 16 CONSECUTIVE outputs; per
// 4-tap group: 1 new ds_read_b128 (XOR-swizzled LDS) feeds 64 FMAs.
// Partials go to part[b][tile][seg][2048] with plain float4 stores (NO global
// atomics - cross-XCD atomic RMW goes to HBM at ~500 GB/s, was the r5
// bottleneck); k_reduce sums the active segs.
#define RTILE 2048     // outputs per tile (128 thr x 16)
#define RCT   256      // taps per chunk
#define RKTH  128      // threads
#define RCH   4        // chunks per block segment
#define RMAXSEG 16     // ceil(63 / RCH)
#define NTILES (NSAMP / RTILE)   // 25 per batch
#define RWIN  (RTILE + RCT)      // 2304 floats
#define RWIN4 (RWIN / 4)         // 576 float4 (multiple of 8 -> swizzle closed)

__device__ __forceinline__ int swz4(int F) { return F ^ ((F >> 3) & 7); }

template <int ATOMIC>
__global__ __launch_bounds__(RKTH) void k_reverb3(const float* __restrict__ sig,
                                                  const float* __restrict__ imp,
                                                  float* __restrict__ dst) {
    __shared__ __align__(16) float s_sig[RWIN];

    int bid  = blockIdx.x;
    int seg  = bid % RMAXSEG;
    int bt   = bid / RMAXSEG;
    int b    = bt / NTILES;
    int tile = bt % NTILES;
    int P0   = tile * RTILE;
    int nch  = (P0 + RTILE) / RCT;             // taps needed: t <= P0+RTILE-1
    if (nch > 63) nch = 63;                    // imp zero beyond 16128
    int c0 = seg * RCH;
    if (c0 >= nch) return;
    int c1 = c0 + RCH; if (c1 > nch) c1 = nch;

    int tid = threadIdx.x;
    const float* sb = sig + b * NSAMP;

    float af[16];
    #pragma unroll
    for (int o = 0; o < 16; ++o) af[o] = 0.f;

    int Fbase = 4 * tid + (RCT / 4 - 1);       // 4*tid + 63

    for (int c = c0; c < c1; ++c) {
        int T0 = c * RCT;
        int W0 = P0 - T0 - RCT;                // logical window float l <-> sig[W0 + l]
        if (W0 >= 0) {
            #pragma unroll
            for (int it = 0; it < 5; ++it) {
                int F = tid + RKTH * it;
                if (F < RWIN4)
                    *reinterpret_cast<float4*>(&s_sig[4 * swz4(F)]) =
                        *reinterpret_cast<const float4*>(&sb[W0 + 4 * F]);
            }
        } else {
            for (int l = tid; l < RWIN; l += RKTH) {
                int idx = W0 + l;
                float v = (idx >= 0) ? sb[idx] : 0.0f;
                s_sig[4 * swz4(l >> 2) + (l & 3)] = v;
            }
        }
        __syncthreads();

        const float4* imp4 = reinterpret_cast<const float4*>(imp + T0);  // uniform -> s_load
        float w_[20];
        #pragma unroll
        for (int k = 0; k < 5; ++k) {
            float4 v = *reinterpret_cast<const float4*>(&s_sig[4 * swz4(Fbase + k)]);
            w_[4 * k + 0] = v.x; w_[4 * k + 1] = v.y;
            w_[4 * k + 2] = v.z; w_[4 * k + 3] = v.w;
        }
        #pragma unroll 8
        for (int g = 0; g < RCT / 4; ++g) {
            float4 iq = imp4[g];
            #pragma unroll
            for (int o = 0; o < 16; ++o) {
                af[o] += iq.x * w_[o + 4];
                af[o] += iq.y * w_[o + 3];
                af[o] += iq.z * w_[o + 2];
                af[o] += iq.w * w_[o + 1];
            }
            if (g < RCT / 4 - 1) {
                float4 nv = *reinterpret_cast<const float4*>(&s_sig[4 * swz4(Fbase - 1 - g)]);
                #pragma unroll
                for (int m = 19; m >= 4; --m) w_[m] = w_[m - 4];
                w_[0] = nv.x; w_[1] = nv.y; w_[2] = nv.z; w_[3] = nv.w;
            }
        }
        __syncthreads();
    }

    if (ATOMIC) {
        float* ob = dst + b * NSAMP + P0 + 16 * tid;
        #pragma unroll
        for (int o = 0; o < 16; ++o) atomicAdd(&ob[o], af[o]);
    } else {
        // part[b][tile][seg][2048], plain coalesced stores
        float* pb = dst + (((b * NTILES + tile) * RMAXSEG + seg) * RTILE) + 16 * tid;
        #pragma unroll
        for (int o = 0; o < 4; ++o)
            *reinterpret_cast<float4*>(&pb[4 * o]) =
                *reinterpret_cast<float4*>(&af[4 * o]);
    }
}

// --- sum active segs: out[b][tile*2048 + x] = sum_s part[b][tile][s][x] ---
__global__ __launch_bounds__(256) void k_reduce(const float* __restrict__ part,
                                                float* __restrict__ out) {
    int q = blockIdx.x * blockDim.x + threadIdx.x;   // float4 index, 102400 total
    int b    = q / (NSAMP / 4);
    int rem  = q % (NSAMP / 4);
    int tile = rem / (RTILE / 4);
    int off4 = rem % (RTILE / 4);
    int nch  = (tile + 1) * (RTILE / RCT) * 1;       // 8*(tile+1)
    nch = (8 * (tile + 1) < 63) ? 8 * (tile + 1) : 63;
    int nsg  = (nch + RCH - 1) / RCH;

    const float4* p4 = reinterpret_cast<const float4*>(part) +
                       ((b * NTILES + tile) * RMAXSEG) * (RTILE / 4) + off4;
    float4 s = {0.f, 0.f, 0.f, 0.f};
    for (int sgi = 0; sgi < nsg; ++sgi) {
        float4 v = p4[sgi * (RTILE / 4)];
        s.x += v.x; s.y += v.y; s.z += v.z; s.w += v.w;
    }
    reinterpret_cast<float4*>(out)[q] = s;
}

extern "C" void kernel_launch(void* const* d_in, const int* in_sizes, int n_in,
                              void* d_out, int out_size, void* d_ws, size_t ws_size,
                              hipStream_t stream) {
    const float* amp_param   = (const float*)d_in[0];
    const float* noise_param = (const float*)d_in[1];
    const float* pitch       = (const float*)d_in[2];
    const float* noise       = (const float*)d_in[3];
    const float* rn          = (const float*)d_in[4];
    const float* decay       = (const float*)d_in[5];
    const float* wet         = (const float*)d_in[6];
    float* out = (float*)d_out;

    char* ws = (char*)d_ws;
    double* prefix = (double*)(ws + OFF_PREFIX);
    float*  amps   = (float*)(ws + OFF_AMPS);
    float*  nz     = (float*)(ws + OFF_NZ);
    float*  sig    = (float*)(ws + OFF_SIG);
    float*  imp    = (float*)(ws + OFF_IMP);
    float*  part   = (float*)(ws + OFF_PART);

    k_prefix<<<dim3(1), dim3(64), 0, stream>>>(pitch, prefix);
    k_imp<<<dim3(IMPN / 256), dim3(256), 0, stream>>>(rn, decay, wet, imp);
    k_frame<<<dim3(NBATCH * NFRAME), dim3(128), 0, stream>>>(amp_param, noise_param, pitch, noise, amps, nz);
    k_harm<<<dim3(NBATCH * NFRAME), dim3(128), 0, stream>>>(pitch, prefix, amps, nz, sig);

    if (ws_size >= (size_t)WS_NEED) {
        k_reverb3<0><<<dim3(NBATCH * NTILES * RMAXSEG), dim3(RKTH), 0, stream>>>(sig, imp, part);
        k_reduce<<<dim3(NBATCH * NSAMP / 4 / 256), dim3(256), 0, stream>>>(part, out);
    } else {
        hipMemsetAsync(out, 0, (size_t)out_size * sizeof(float), stream);
        k_reverb3<1><<<dim3(NBATCH * NTILES * RMAXSEG), dim3(RKTH), 0, stream>>>(sig, imp, out);
    }
}